// Round 11
// baseline (219.259 us; speedup 1.0000x reference)
//
#include <hip/hip_runtime.h>
#include <hip/hip_fp16.h>
#include <cstdint>

#define N_NODES 100000
#define H_HEADS 4
#define C_FEATS 32
#define HC 128          // H*C
#define E_EDGES 1600000
#define IN_F 256
#define NEG_SLOPE 0.2f

#define BSHIFT 7                              // bucket = dst >> 7 (128 nodes/bucket)
#define NBUCK 782                             // ceil(100000/128)
#define NREG 8                                // XCD-private region replicas (blockIdx&7)
#define CAPB8 384                             // words per (region,bucket): Poisson(256)+8sd
#define PH1_CHUNK 4096                        // edges per bucket block
#define PH1_BLOCKS ((E_EDGES + PH1_CHUNK - 1) / PH1_CHUNK)   // 391
#define GEMM_BLOCKS ((N_NODES + 127) / 128)   // 782 (128 rows/block, 2 tiles/wave)
#define HALFCAP 1408                          // LDS csr capacity per 64-node sub-block
#define SWCAP 384                             // staged weights per wave (mean 256, +8 sd)

typedef _Float16 half8 __attribute__((ext_vector_type(8)));
typedef _Float16 half4v __attribute__((ext_vector_type(4)));
typedef float f32x4 __attribute__((ext_vector_type(4)));
typedef int i32x4 __attribute__((ext_vector_type(4)));

// ---------------- prep: W16t[c][k] = (fp16) W[k][c]; block 0 zeroes gcnt ----
__global__ __launch_bounds__(256) void prep_w(const float* __restrict__ W,
                                              _Float16* __restrict__ W16t,
                                              int* __restrict__ gcnt) {
    int c = blockIdx.x;      // 0..127
    int k = threadIdx.x;     // 0..255
    W16t[c * IN_F + k] = (_Float16)W[k * HC + c];
    if (c == 0)
        for (int i = k; i < NREG * NBUCK; i += 256) gcnt[i] = 0;
}

// ---------------- fused: bucket-sort blocks + MFMA-GEMM blocks --------------
// Bucket path: per-edge direct atomicAdd on the XCD-private gcnt region
// (blockIdx&7 -> same-XCD L2 under round-robin dispatch) + one 4B write into
// the region bucket. No LDS, no barriers. Tail block guarded (cnt_e).
// GEMM path: 2 row-tiles per wave (128 rows/block): each W16t fragment feeds
// two independent MFMAs -> half the L2 W-traffic, double the MFMA ILP.
__global__ __launch_bounds__(256, 4) void gemm_bucket(const float* __restrict__ x,
                                                      const _Float16* __restrict__ W16t,
                                                      const float* __restrict__ attn_l,
                                                      const float* __restrict__ attn_r,
                                                      const int* __restrict__ src,
                                                      const int* __restrict__ dst,
                                                      _Float16* __restrict__ feat16,
                                                      float* __restrict__ el,
                                                      float* __restrict__ er,
                                                      int* __restrict__ gcnt,
                                                      unsigned* __restrict__ bucket) {
    const int t = threadIdx.x;

    if (blockIdx.x < PH1_BLOCKS) {
        // ---- bucket-sort path: 16 edges/thread, direct region atomics ----
        const int rg    = blockIdx.x & (NREG - 1);
        const int base  = blockIdx.x * PH1_CHUNK;
        const int cnt_e = min(PH1_CHUNK, E_EDGES - base);   // tail guard!
        const i32x4* d4 = (const i32x4*)(dst + base);
        const i32x4* s4 = (const i32x4*)(src + base);
        #pragma unroll
        for (int j = 0; j < 4; ++j) {
            int idx = t + j * 256;                 // int4 index, < 1024
            int e0  = idx * 4;
            if (e0 + 3 < cnt_e) {
                i32x4 d = __builtin_nontemporal_load(&d4[idx]);
                i32x4 s = __builtin_nontemporal_load(&s4[idx]);
                #pragma unroll
                for (int k = 0; k < 4; ++k) {
                    int dj = d[k];
                    int bk = dj >> BSHIFT;
                    unsigned w = ((unsigned)(dj & ((1 << BSHIFT) - 1)) << 24) | (unsigned)s[k];
                    int slot = atomicAdd(&gcnt[rg * NBUCK + bk], 1);
                    if (slot < CAPB8)
                        bucket[((size_t)rg * NBUCK + bk) * CAPB8 + slot] = w;
                }
            } else if (e0 < cnt_e) {
                for (int k = 0; k < 4 && e0 + k < cnt_e; ++k) {
                    int dj = dst[base + e0 + k];
                    int sj = src[base + e0 + k];
                    int bk = dj >> BSHIFT;
                    unsigned w = ((unsigned)(dj & ((1 << BSHIFT) - 1)) << 24) | (unsigned)sj;
                    int slot = atomicAdd(&gcnt[rg * NBUCK + bk], 1);
                    if (slot < CAPB8)
                        bucket[((size_t)rg * NBUCK + bk) * CAPB8 + slot] = w;
                }
            }
        }
        return;
    }

    // ---- GEMM path: 2 row-tiles per wave ----
    const int blk  = blockIdx.x - PH1_BLOCKS;
    const int w    = t >> 6;
    const int lane = t & 63;
    const int lrow = lane & 15;
    const int kq   = lane >> 4;                      // 0..3
    const int gr0  = blk * 128 + w * 32 + lrow;      // tile 0 row
    const int gr1  = gr0 + 16;                       // tile 1 row
    const int r0   = gr0 < N_NODES ? gr0 : N_NODES - 1;
    const int r1   = gr1 < N_NODES ? gr1 : N_NODES - 1;

    f32x4 acc0[8], acc1[8];
    #pragma unroll
    for (int c = 0; c < 8; ++c) {
        acc0[c] = (f32x4){0.f, 0.f, 0.f, 0.f};
        acc1[c] = (f32x4){0.f, 0.f, 0.f, 0.f};
    }

    #pragma unroll
    for (int s = 0; s < 8; ++s) {
        const int k0 = s * 32 + kq * 8;
        float4 u0 = *(const float4*)&x[(size_t)r0 * IN_F + k0];
        float4 u1 = *(const float4*)&x[(size_t)r0 * IN_F + k0 + 4];
        float4 v0 = *(const float4*)&x[(size_t)r1 * IN_F + k0];
        float4 v1 = *(const float4*)&x[(size_t)r1 * IN_F + k0 + 4];
        half8 af0, af1;
        af0[0] = (_Float16)u0.x; af0[1] = (_Float16)u0.y;
        af0[2] = (_Float16)u0.z; af0[3] = (_Float16)u0.w;
        af0[4] = (_Float16)u1.x; af0[5] = (_Float16)u1.y;
        af0[6] = (_Float16)u1.z; af0[7] = (_Float16)u1.w;
        af1[0] = (_Float16)v0.x; af1[1] = (_Float16)v0.y;
        af1[2] = (_Float16)v0.z; af1[3] = (_Float16)v0.w;
        af1[4] = (_Float16)v1.x; af1[5] = (_Float16)v1.y;
        af1[6] = (_Float16)v1.z; af1[7] = (_Float16)v1.w;
        #pragma unroll
        for (int c = 0; c < 8; ++c) {
            half8 bf = *(const half8*)&W16t[(size_t)(c * 16 + lrow) * IN_F + k0];
            acc0[c] = __builtin_amdgcn_mfma_f32_16x16x32_f16(bf, af0, acc0[c], 0, 0, 0);
            acc1[c] = __builtin_amdgcn_mfma_f32_16x16x32_f16(bf, af1, acc1[c], 0, 0, 0);
        }
    }

    // epilogue per tile: fp16 store + fused el/er (col of acc[c][j] = c*16+kq*4+j)
    #pragma unroll
    for (int tile = 0; tile < 2; ++tile) {
        const int gr = tile == 0 ? gr0 : gr1;
        f32x4* acc = tile == 0 ? acc0 : acc1;
        float pl[4] = {0.f, 0.f, 0.f, 0.f}, pr[4] = {0.f, 0.f, 0.f, 0.f};
        #pragma unroll
        for (int c = 0; c < 8; ++c) {
            const int h = c >> 1;
            #pragma unroll
            for (int j = 0; j < 4; ++j) {
                const int col = c * 16 + kq * 4 + j;
                pl[h] += acc[c][j] * attn_l[col];
                pr[h] += acc[c][j] * attn_r[col];
            }
        }
        #pragma unroll
        for (int h = 0; h < 4; ++h) {   // reduce over the 4 kq groups (lane bits 4,5)
            pl[h] += __shfl_xor(pl[h], 16, 64); pl[h] += __shfl_xor(pl[h], 32, 64);
            pr[h] += __shfl_xor(pr[h], 16, 64); pr[h] += __shfl_xor(pr[h], 32, 64);
        }
        if (gr < N_NODES) {
            #pragma unroll
            for (int c = 0; c < 8; ++c) {
                half4v hv;
                hv[0] = (_Float16)acc[c][0]; hv[1] = (_Float16)acc[c][1];
                hv[2] = (_Float16)acc[c][2]; hv[3] = (_Float16)acc[c][3];
                *(half4v*)&feat16[(size_t)gr * HC + c * 16 + kq * 4] = hv;
            }
            if (kq == 0) {
                *(float4*)&el[gr * 4] = make_float4(pl[0], pl[1], pl[2], pl[3]);
                *(float4*)&er[gr * 4] = make_float4(pr[0], pr[1], pr[2], pr[3]);
            }
        }
    }
}

// ---------------- gather: in-LDS CSR + wave-wide weights + 4-node agg -------
__global__ __launch_bounds__(256) void gat_gather(const int* __restrict__ gcnt,
                                                  const unsigned* __restrict__ bucket,
                                                  const float* __restrict__ el,
                                                  const float* __restrict__ er,
                                                  const _Float16* __restrict__ feat16,
                                                  const float* __restrict__ bias,
                                                  float* __restrict__ out) {
    __shared__ int   cnt[64];
    __shared__ int   off[64];
    __shared__ int   lcsr[HALFCAP];
    __shared__ float s_w[4][SWCAP][4];

    const int b   = blockIdx.x >> 1;
    const int sub = blockIdx.x & 1;
    const int t   = threadIdx.x;
    const int n0  = (b << BSHIFT) + sub * 64;

    if (t < 64) cnt[t] = 0;
    __syncthreads();
    #pragma unroll
    for (int rr = 0; rr < NREG; ++rr) {
        const int m = min(gcnt[rr * NBUCK + b], CAPB8);
        const size_t rbase = ((size_t)rr * NBUCK + b) * CAPB8;
        for (int i = t; i < m; i += 256) {
            unsigned wrd = bucket[rbase + i];
            int nb = wrd >> 24;
            if ((nb >> 6) == sub) atomicAdd(&cnt[nb & 63], 1);
        }
    }
    __syncthreads();
    if (t < 64) {   // exclusive scan of 64 counts within wave 0
        int v = cnt[t];
        int inc = v;
        #pragma unroll
        for (int o = 1; o < 64; o <<= 1) {
            int u = __shfl_up(inc, o, 64);
            if (t >= o) inc += u;
        }
        off[t] = inc - v;
        cnt[t] = 0;     // reuse as scatter cursor (restored to count below)
    }
    __syncthreads();
    #pragma unroll
    for (int rr = 0; rr < NREG; ++rr) {
        const int m = min(gcnt[rr * NBUCK + b], CAPB8);
        const size_t rbase = ((size_t)rr * NBUCK + b) * CAPB8;
        for (int i = t; i < m; i += 256) {
            unsigned wrd = bucket[rbase + i];
            int nb = wrd >> 24;
            if ((nb >> 6) == sub) {
                int r = atomicAdd(&cnt[nb & 63], 1);
                int p = off[nb & 63] + r;
                if (p < HALFCAP) lcsr[p] = (int)(wrd & 0xBFFFFFFFu);
            }
        }
    }
    __syncthreads();

    const int wv   = t >> 6;
    const int lane = t & 63;
    const int q    = lane >> 4;      // quarter = node slot
    const int ql   = lane & 15;
    const int h    = ql >> 2;

    // ---- wave-wide weight phase: edges [wbase, wbase+nE) of this wave ----
    const int wbase = off[wv * 16];
    const int wlast = wv * 16 + 15;
    const int nE    = min(off[wlast] + cnt[wlast] - wbase, SWCAP);
    for (int i = lane; i < nE; i += 64) {
        int wrd = lcsr[wbase + i];
        int s   = wrd & 0xFFFFFF;
        int nl  = (wrd >> 24) & 63;
        float4 a  = *(const float4*)&el[(size_t)s * 4];
        float4 bb = *(const float4*)&er[(size_t)(n0 + nl) * 4];
        float v0 = a.x + bb.x, v1 = a.y + bb.y, v2 = a.z + bb.z, v3 = a.w + bb.w;
        v0 = fmaxf(v0, NEG_SLOPE * v0); v1 = fmaxf(v1, NEG_SLOPE * v1);
        v2 = fmaxf(v2, NEG_SLOPE * v2); v3 = fmaxf(v3, NEG_SLOPE * v3);
        float4 w4;
        w4.x = __expf(v0); w4.y = __expf(v1); w4.z = __expf(v2); w4.w = __expf(v3);
        *(float4*)&s_w[wv][i][0] = w4;
    }
    __builtin_amdgcn_sched_barrier(0);   // wave-coherent LDS: DS pipe in-order per wave

    // bias per lane is fixed: channels (ql&3)*8..+7 of head h
    float bv[8];
    #pragma unroll
    for (int k = 0; k < 8; ++k) bv[k] = bias[h * C_FEATS + (ql & 3) * 8 + k];

    // ---- aggregation: 4 rounds x 4 nodes (one per quarter) ----
    for (int r0 = 0; r0 < 16; r0 += 4) {
        const int nl   = wv * 16 + r0 + q;
        const int n    = n0 + nl;
        const int bofs = off[nl];
        const int widx = bofs - wbase;
        int dg = cnt[nl];
        dg = min(dg, SWCAP - widx);
        if (dg < 0 || n >= N_NODES) dg = 0;

        float ac[8] = {0.f, 0.f, 0.f, 0.f, 0.f, 0.f, 0.f, 0.f};
        float sh = 0.f;
        #pragma unroll 4
        for (int j = 0; j < dg; ++j) {
            float wgt = s_w[wv][widx + j][h];
            int s = lcsr[bofs + j] & 0xFFFFFF;
            half8 f = *(const half8*)&feat16[(size_t)s * HC + ql * 8];
            #pragma unroll
            for (int k = 0; k < 8; ++k) ac[k] += wgt * (float)f[k];
            if ((ql & 3) == 0) sh += wgt;
        }
        __builtin_amdgcn_sched_barrier(0);

        // per-head denominator lives at lanes ql%4==0; broadcast within quarter
        float d = __shfl(sh, (lane & 48) | (ql & 12), 64);
        float inv = d > 0.f ? 1.f / d : 0.f;
        float o[8];
        #pragma unroll
        for (int k = 0; k < 8; ++k) o[k] = ac[k] * inv + bv[k];
        // mean over heads: sum across ql bits 2,3 (stays inside the quarter)
        #pragma unroll
        for (int k = 0; k < 8; ++k) {
            o[k] += __shfl_xor(o[k], 4, 64);
            o[k] += __shfl_xor(o[k], 8, 64);
        }
        if (n < N_NODES && ql < 4) {
            float4 r1, r2;
            r1.x = fmaxf(o[0] * 0.25f, 0.f); r1.y = fmaxf(o[1] * 0.25f, 0.f);
            r1.z = fmaxf(o[2] * 0.25f, 0.f); r1.w = fmaxf(o[3] * 0.25f, 0.f);
            r2.x = fmaxf(o[4] * 0.25f, 0.f); r2.y = fmaxf(o[5] * 0.25f, 0.f);
            r2.z = fmaxf(o[6] * 0.25f, 0.f); r2.w = fmaxf(o[7] * 0.25f, 0.f);
            *(float4*)&out[(size_t)n * C_FEATS + ql * 8]     = r1;
            *(float4*)&out[(size_t)n * C_FEATS + ql * 8 + 4] = r2;
        }
    }
}

extern "C" void kernel_launch(void* const* d_in, const int* in_sizes, int n_in,
                              void* d_out, int out_size, void* d_ws, size_t ws_size,
                              hipStream_t stream) {
    const float* x      = (const float*)d_in[0];
    const int*   src    = (const int*)d_in[1];
    const int*   dst    = (const int*)d_in[2];
    const float* W      = (const float*)d_in[3];
    const float* attn_l = (const float*)d_in[4];
    const float* attn_r = (const float*)d_in[5];
    const float* bias   = (const float*)d_in[6];
    float* out = (float*)d_out;

    char* ws = (char*)d_ws;
    const size_t FEAT16_B = (size_t)N_NODES * HC * 2;      // 25.6 MB
    const size_t NH_B     = (size_t)N_NODES * H_HEADS * 4; // 1.6 MB
    size_t off = 0;
    _Float16* feat16 = (_Float16*)(ws + off); off += FEAT16_B;
    float* el        = (float*)(ws + off);    off += NH_B;
    float* er        = (float*)(ws + off);    off += NH_B;
    _Float16* W16t   = (_Float16*)(ws + off); off += (size_t)HC * IN_F * 2;
    int*   gcnt      = (int*)(ws + off);      off += (size_t)NREG * NBUCK * 4;
    off = (off + 255) & ~(size_t)255;
    unsigned* bucket = (unsigned*)(ws + off); off += (size_t)NREG * NBUCK * CAPB8 * 4; // 9.6 MB

    prep_w<<<HC, IN_F, 0, stream>>>(W, W16t, gcnt);
    gemm_bucket<<<PH1_BLOCKS + GEMM_BLOCKS, 256, 0, stream>>>(
        x, W16t, attn_l, attn_r, src, dst, feat16, el, er, gcnt, bucket);
    gat_gather<<<NBUCK * 2, 256, 0, stream>>>(gcnt, bucket, el, er,
                                              feat16, bias, out);
}

// Round 12
// 153.675 us; speedup vs baseline: 1.4268x; 1.4268x over previous
//
#include <hip/hip_runtime.h>
#include <hip/hip_fp16.h>
#include <cstdint>

#define N_NODES 100000
#define H_HEADS 4
#define C_FEATS 32
#define HC 128          // H*C
#define E_EDGES 1600000
#define IN_F 256
#define NEG_SLOPE 0.2f

#define BSHIFT 7                              // bucket = dst >> 7 (128 nodes/bucket)
#define NBUCK 782                             // ceil(100000/128)
#define NREG 8                                // XCD-private region replicas (blockIdx&7)
#define CAPB8 384                             // words per (region,bucket): Poisson(256)+8sd
#define PH1_CHUNK 4096                        // edges per bucket block
#define PH1_BLOCKS ((E_EDGES + PH1_CHUNK - 1) / PH1_CHUNK)   // 391
#define GEMM_BLOCKS ((N_NODES + 127) / 128)   // 782 (128 rows/block, 2 tiles/wave)
#define HALFCAP 1408                          // LDS csr capacity per 64-node sub-block
#define SWCAP 384                             // staged weights per wave (mean 256, +8 sd)

typedef _Float16 half8 __attribute__((ext_vector_type(8)));
typedef _Float16 half4v __attribute__((ext_vector_type(4)));
typedef float f32x4 __attribute__((ext_vector_type(4)));

// ---------------- prep: W16t[c][k] = (fp16) W[k][c]; block 0 zeroes gcnt ----
__global__ __launch_bounds__(256) void prep_w(const float* __restrict__ W,
                                              _Float16* __restrict__ W16t,
                                              int* __restrict__ gcnt) {
    int c = blockIdx.x;      // 0..127
    int k = threadIdx.x;     // 0..255
    W16t[c * IN_F + k] = (_Float16)W[k * HC + c];
    if (c == 0)
        for (int i = k; i < NREG * NBUCK; i += 256) gcnt[i] = 0;
}

// ---------------- fused: bucket-sort blocks + MFMA-GEMM blocks --------------
// Bucket path (R9 form): LDS histogram -> one gcnt atomic per (block,bucket)
// -> contiguous ~5-word runs per line in the XCD-private region (blockIdx&7).
// GEMM path: 2 row-tiles per wave (128 rows/block): each W16t fragment feeds
// two independent MFMAs -> half the L2 W-traffic, double the MFMA ILP.
__global__ __launch_bounds__(256, 4) void gemm_bucket(const float* __restrict__ x,
                                                      const _Float16* __restrict__ W16t,
                                                      const float* __restrict__ attn_l,
                                                      const float* __restrict__ attn_r,
                                                      const int* __restrict__ src,
                                                      const int* __restrict__ dst,
                                                      _Float16* __restrict__ feat16,
                                                      float* __restrict__ el,
                                                      float* __restrict__ er,
                                                      int* __restrict__ gcnt,
                                                      unsigned* __restrict__ bucket) {
    __shared__ int hist[NBUCK];
    const int t = threadIdx.x;

    if (blockIdx.x < PH1_BLOCKS) {
        // ---- bucket-sort path ----
        const int rg    = blockIdx.x & (NREG - 1);
        const int base  = blockIdx.x * PH1_CHUNK;
        const int cnt_e = min(PH1_CHUNK, E_EDGES - base);   // tail guard
        for (int i = t; i < NBUCK; i += 256) hist[i] = 0;
        __syncthreads();

        unsigned w[16]; int bk[16];
        #pragma unroll
        for (int j = 0; j < 16; ++j) {
            int i = t + j * 256;
            bk[j] = -1;
            if (i < cnt_e) {
                int d = dst[base + i];
                int s = src[base + i];
                bk[j] = d >> BSHIFT;
                w[j] = ((unsigned)(d & ((1 << BSHIFT) - 1)) << 24) | (unsigned)s;
                atomicAdd(&hist[bk[j]], 1);
            }
        }
        __syncthreads();
        // reserve dense runs in the region: hist[b] becomes the write cursor
        for (int i = t; i < NBUCK; i += 256) {
            int c = hist[i];
            hist[i] = (c > 0) ? atomicAdd(&gcnt[rg * NBUCK + i], c) : 0;
        }
        __syncthreads();
        #pragma unroll
        for (int j = 0; j < 16; ++j) {
            if (bk[j] >= 0) {
                int slot = atomicAdd(&hist[bk[j]], 1);
                if (slot < CAPB8)
                    bucket[((size_t)rg * NBUCK + bk[j]) * CAPB8 + slot] = w[j];
            }
        }
        return;
    }

    // ---- GEMM path: 2 row-tiles per wave ----
    const int blk  = blockIdx.x - PH1_BLOCKS;
    const int w    = t >> 6;
    const int lane = t & 63;
    const int lrow = lane & 15;
    const int kq   = lane >> 4;                      // 0..3
    const int gr0  = blk * 128 + w * 32 + lrow;      // tile 0 row
    const int gr1  = gr0 + 16;                       // tile 1 row
    const int r0   = gr0 < N_NODES ? gr0 : N_NODES - 1;
    const int r1   = gr1 < N_NODES ? gr1 : N_NODES - 1;

    f32x4 acc0[8], acc1[8];
    #pragma unroll
    for (int c = 0; c < 8; ++c) {
        acc0[c] = (f32x4){0.f, 0.f, 0.f, 0.f};
        acc1[c] = (f32x4){0.f, 0.f, 0.f, 0.f};
    }

    #pragma unroll
    for (int s = 0; s < 8; ++s) {
        const int k0 = s * 32 + kq * 8;
        float4 u0 = *(const float4*)&x[(size_t)r0 * IN_F + k0];
        float4 u1 = *(const float4*)&x[(size_t)r0 * IN_F + k0 + 4];
        float4 v0 = *(const float4*)&x[(size_t)r1 * IN_F + k0];
        float4 v1 = *(const float4*)&x[(size_t)r1 * IN_F + k0 + 4];
        half8 af0, af1;
        af0[0] = (_Float16)u0.x; af0[1] = (_Float16)u0.y;
        af0[2] = (_Float16)u0.z; af0[3] = (_Float16)u0.w;
        af0[4] = (_Float16)u1.x; af0[5] = (_Float16)u1.y;
        af0[6] = (_Float16)u1.z; af0[7] = (_Float16)u1.w;
        af1[0] = (_Float16)v0.x; af1[1] = (_Float16)v0.y;
        af1[2] = (_Float16)v0.z; af1[3] = (_Float16)v0.w;
        af1[4] = (_Float16)v1.x; af1[5] = (_Float16)v1.y;
        af1[6] = (_Float16)v1.z; af1[7] = (_Float16)v1.w;
        #pragma unroll
        for (int c = 0; c < 8; ++c) {
            half8 bf = *(const half8*)&W16t[(size_t)(c * 16 + lrow) * IN_F + k0];
            acc0[c] = __builtin_amdgcn_mfma_f32_16x16x32_f16(bf, af0, acc0[c], 0, 0, 0);
            acc1[c] = __builtin_amdgcn_mfma_f32_16x16x32_f16(bf, af1, acc1[c], 0, 0, 0);
        }
    }

    // epilogue per tile: fp16 store + fused el/er (col of acc[c][j] = c*16+kq*4+j)
    #pragma unroll
    for (int tile = 0; tile < 2; ++tile) {
        const int gr = tile == 0 ? gr0 : gr1;
        f32x4* acc = tile == 0 ? acc0 : acc1;
        float pl[4] = {0.f, 0.f, 0.f, 0.f}, pr[4] = {0.f, 0.f, 0.f, 0.f};
        #pragma unroll
        for (int c = 0; c < 8; ++c) {
            const int h = c >> 1;
            #pragma unroll
            for (int j = 0; j < 4; ++j) {
                const int col = c * 16 + kq * 4 + j;
                pl[h] += acc[c][j] * attn_l[col];
                pr[h] += acc[c][j] * attn_r[col];
            }
        }
        #pragma unroll
        for (int h = 0; h < 4; ++h) {   // reduce over the 4 kq groups (lane bits 4,5)
            pl[h] += __shfl_xor(pl[h], 16, 64); pl[h] += __shfl_xor(pl[h], 32, 64);
            pr[h] += __shfl_xor(pr[h], 16, 64); pr[h] += __shfl_xor(pr[h], 32, 64);
        }
        if (gr < N_NODES) {
            #pragma unroll
            for (int c = 0; c < 8; ++c) {
                half4v hv;
                hv[0] = (_Float16)acc[c][0]; hv[1] = (_Float16)acc[c][1];
                hv[2] = (_Float16)acc[c][2]; hv[3] = (_Float16)acc[c][3];
                *(half4v*)&feat16[(size_t)gr * HC + c * 16 + kq * 4] = hv;
            }
            if (kq == 0) {
                *(float4*)&el[gr * 4] = make_float4(pl[0], pl[1], pl[2], pl[3]);
                *(float4*)&er[gr * 4] = make_float4(pr[0], pr[1], pr[2], pr[3]);
            }
        }
    }
}

// ---------------- gather: in-LDS CSR + wave-wide weights + 4-node agg -------
__global__ __launch_bounds__(256) void gat_gather(const int* __restrict__ gcnt,
                                                  const unsigned* __restrict__ bucket,
                                                  const float* __restrict__ el,
                                                  const float* __restrict__ er,
                                                  const _Float16* __restrict__ feat16,
                                                  const float* __restrict__ bias,
                                                  float* __restrict__ out) {
    __shared__ int   cnt[64];
    __shared__ int   off[64];
    __shared__ int   lcsr[HALFCAP];
    __shared__ float s_w[4][SWCAP][4];

    const int b   = blockIdx.x >> 1;
    const int sub = blockIdx.x & 1;
    const int t   = threadIdx.x;
    const int n0  = (b << BSHIFT) + sub * 64;

    if (t < 64) cnt[t] = 0;
    __syncthreads();
    #pragma unroll
    for (int rr = 0; rr < NREG; ++rr) {
        const int m = min(gcnt[rr * NBUCK + b], CAPB8);
        const size_t rbase = ((size_t)rr * NBUCK + b) * CAPB8;
        for (int i = t; i < m; i += 256) {
            unsigned wrd = bucket[rbase + i];
            int nb = wrd >> 24;
            if ((nb >> 6) == sub) atomicAdd(&cnt[nb & 63], 1);
        }
    }
    __syncthreads();
    if (t < 64) {   // exclusive scan of 64 counts within wave 0
        int v = cnt[t];
        int inc = v;
        #pragma unroll
        for (int o = 1; o < 64; o <<= 1) {
            int u = __shfl_up(inc, o, 64);
            if (t >= o) inc += u;
        }
        off[t] = inc - v;
        cnt[t] = 0;     // reuse as scatter cursor (restored to count below)
    }
    __syncthreads();
    #pragma unroll
    for (int rr = 0; rr < NREG; ++rr) {
        const int m = min(gcnt[rr * NBUCK + b], CAPB8);
        const size_t rbase = ((size_t)rr * NBUCK + b) * CAPB8;
        for (int i = t; i < m; i += 256) {
            unsigned wrd = bucket[rbase + i];
            int nb = wrd >> 24;
            if ((nb >> 6) == sub) {
                int r = atomicAdd(&cnt[nb & 63], 1);
                int p = off[nb & 63] + r;
                if (p < HALFCAP) lcsr[p] = (int)(wrd & 0xBFFFFFFFu);
            }
        }
    }
    __syncthreads();

    const int wv   = t >> 6;
    const int lane = t & 63;
    const int q    = lane >> 4;      // quarter = node slot
    const int ql   = lane & 15;
    const int h    = ql >> 2;

    // ---- wave-wide weight phase: edges [wbase, wbase+nE) of this wave ----
    const int wbase = off[wv * 16];
    const int wlast = wv * 16 + 15;
    const int nE    = min(off[wlast] + cnt[wlast] - wbase, SWCAP);
    for (int i = lane; i < nE; i += 64) {
        int wrd = lcsr[wbase + i];
        int s   = wrd & 0xFFFFFF;
        int nl  = (wrd >> 24) & 63;
        float4 a  = *(const float4*)&el[(size_t)s * 4];
        float4 bb = *(const float4*)&er[(size_t)(n0 + nl) * 4];
        float v0 = a.x + bb.x, v1 = a.y + bb.y, v2 = a.z + bb.z, v3 = a.w + bb.w;
        v0 = fmaxf(v0, NEG_SLOPE * v0); v1 = fmaxf(v1, NEG_SLOPE * v1);
        v2 = fmaxf(v2, NEG_SLOPE * v2); v3 = fmaxf(v3, NEG_SLOPE * v3);
        float4 w4;
        w4.x = __expf(v0); w4.y = __expf(v1); w4.z = __expf(v2); w4.w = __expf(v3);
        *(float4*)&s_w[wv][i][0] = w4;
    }
    __builtin_amdgcn_sched_barrier(0);   // wave-coherent LDS: DS pipe in-order per wave

    // bias per lane is fixed: channels (ql&3)*8..+7 of head h
    float bv[8];
    #pragma unroll
    for (int k = 0; k < 8; ++k) bv[k] = bias[h * C_FEATS + (ql & 3) * 8 + k];

    // ---- aggregation: 4 rounds x 4 nodes (one per quarter) ----
    for (int r0 = 0; r0 < 16; r0 += 4) {
        const int nl   = wv * 16 + r0 + q;
        const int n    = n0 + nl;
        const int bofs = off[nl];
        const int widx = bofs - wbase;
        int dg = cnt[nl];
        dg = min(dg, SWCAP - widx);
        if (dg < 0 || n >= N_NODES) dg = 0;

        float ac[8] = {0.f, 0.f, 0.f, 0.f, 0.f, 0.f, 0.f, 0.f};
        float sh = 0.f;
        #pragma unroll 4
        for (int j = 0; j < dg; ++j) {
            float wgt = s_w[wv][widx + j][h];
            int s = lcsr[bofs + j] & 0xFFFFFF;
            half8 f = *(const half8*)&feat16[(size_t)s * HC + ql * 8];
            #pragma unroll
            for (int k = 0; k < 8; ++k) ac[k] += wgt * (float)f[k];
            if ((ql & 3) == 0) sh += wgt;
        }
        __builtin_amdgcn_sched_barrier(0);

        // per-head denominator lives at lanes ql%4==0; broadcast within quarter
        float d = __shfl(sh, (lane & 48) | (ql & 12), 64);
        float inv = d > 0.f ? 1.f / d : 0.f;
        float o[8];
        #pragma unroll
        for (int k = 0; k < 8; ++k) o[k] = ac[k] * inv + bv[k];
        // mean over heads: sum across ql bits 2,3 (stays inside the quarter)
        #pragma unroll
        for (int k = 0; k < 8; ++k) {
            o[k] += __shfl_xor(o[k], 4, 64);
            o[k] += __shfl_xor(o[k], 8, 64);
        }
        if (n < N_NODES && ql < 4) {
            float4 r1, r2;
            r1.x = fmaxf(o[0] * 0.25f, 0.f); r1.y = fmaxf(o[1] * 0.25f, 0.f);
            r1.z = fmaxf(o[2] * 0.25f, 0.f); r1.w = fmaxf(o[3] * 0.25f, 0.f);
            r2.x = fmaxf(o[4] * 0.25f, 0.f); r2.y = fmaxf(o[5] * 0.25f, 0.f);
            r2.z = fmaxf(o[6] * 0.25f, 0.f); r2.w = fmaxf(o[7] * 0.25f, 0.f);
            *(float4*)&out[(size_t)n * C_FEATS + ql * 8]     = r1;
            *(float4*)&out[(size_t)n * C_FEATS + ql * 8 + 4] = r2;
        }
    }
}

extern "C" void kernel_launch(void* const* d_in, const int* in_sizes, int n_in,
                              void* d_out, int out_size, void* d_ws, size_t ws_size,
                              hipStream_t stream) {
    const float* x      = (const float*)d_in[0];
    const int*   src    = (const int*)d_in[1];
    const int*   dst    = (const int*)d_in[2];
    const float* W      = (const float*)d_in[3];
    const float* attn_l = (const float*)d_in[4];
    const float* attn_r = (const float*)d_in[5];
    const float* bias   = (const float*)d_in[6];
    float* out = (float*)d_out;

    char* ws = (char*)d_ws;
    const size_t FEAT16_B = (size_t)N_NODES * HC * 2;      // 25.6 MB
    const size_t NH_B     = (size_t)N_NODES * H_HEADS * 4; // 1.6 MB
    size_t off = 0;
    _Float16* feat16 = (_Float16*)(ws + off); off += FEAT16_B;
    float* el        = (float*)(ws + off);    off += NH_B;
    float* er        = (float*)(ws + off);    off += NH_B;
    _Float16* W16t   = (_Float16*)(ws + off); off += (size_t)HC * IN_F * 2;
    int*   gcnt      = (int*)(ws + off);      off += (size_t)NREG * NBUCK * 4;
    off = (off + 255) & ~(size_t)255;
    unsigned* bucket = (unsigned*)(ws + off); off += (size_t)NREG * NBUCK * CAPB8 * 4; // 9.6 MB

    prep_w<<<HC, IN_F, 0, stream>>>(W, W16t, gcnt);
    gemm_bucket<<<PH1_BLOCKS + GEMM_BLOCKS, 256, 0, stream>>>(
        x, W16t, attn_l, attn_r, src, dst, feat16, el, er, gcnt, bucket);
    gat_gather<<<NBUCK * 2, 256, 0, stream>>>(gcnt, bucket, el, er,
                                              feat16, bias, out);
}

// Round 13
// 149.218 us; speedup vs baseline: 1.4694x; 1.0299x over previous
//
#include <hip/hip_runtime.h>
#include <hip/hip_fp16.h>
#include <cstdint>

#define N_NODES 100000
#define H_HEADS 4
#define C_FEATS 32
#define HC 128          // H*C
#define E_EDGES 1600000
#define IN_F 256
#define NEG_SLOPE 0.2f

#define BSHIFT 7                              // bucket = dst >> 7 (128 nodes/bucket)
#define NBUCK 782                             // ceil(100000/128)
#define NREG 8                                // XCD-private region replicas (blockIdx&7)
#define CAPB8 384                             // words per (region,bucket): Poisson(256)+8sd
#define PH1_CHUNK 4096                        // edges per bucket block
#define PH1_BLOCKS ((E_EDGES + PH1_CHUNK - 1) / PH1_CHUNK)   // 391
#define GEMM_BLOCKS ((N_NODES + 127) / 128)   // 782 (128 rows/block, 2 tiles/wave)
#define HALFCAP 1408                          // LDS csr capacity per 64-node sub-block
#define SWCAP 384                             // staged weights per wave (mean 256, +8 sd)

typedef _Float16 half8 __attribute__((ext_vector_type(8)));
typedef _Float16 half4v __attribute__((ext_vector_type(4)));
typedef float f32x4 __attribute__((ext_vector_type(4)));
typedef int i32x4 __attribute__((ext_vector_type(4)));

// ---------------- prep: W16t[c][k] = (fp16) W[k][c]; block 0 zeroes gcnt ----
__global__ __launch_bounds__(256) void prep_w(const float* __restrict__ W,
                                              _Float16* __restrict__ W16t,
                                              int* __restrict__ gcnt) {
    int c = blockIdx.x;      // 0..127
    int k = threadIdx.x;     // 0..255
    W16t[c * IN_F + k] = (_Float16)W[k * HC + c];
    if (c == 0)
        for (int i = k; i < NREG * NBUCK; i += 256) gcnt[i] = 0;
}

// ---------------- fused: bucket-sort blocks + MFMA-GEMM blocks --------------
// Bucket path (R9 form): LDS histogram -> one gcnt atomic per (block,bucket)
// -> contiguous ~5-word runs per line in the XCD-private region (blockIdx&7).
// GEMM path: 2 row-tiles per wave. NO min-wave launch bound: the allocator
// needs >64 VGPRs to keep the 32 independent x-loads per step-group in
// flight (R12's __launch_bounds__(256,4) capped at 64 and serialized them).
__global__ __launch_bounds__(256) void gemm_bucket(const float* __restrict__ x,
                                                   const _Float16* __restrict__ W16t,
                                                   const float* __restrict__ attn_l,
                                                   const float* __restrict__ attn_r,
                                                   const int* __restrict__ src,
                                                   const int* __restrict__ dst,
                                                   _Float16* __restrict__ feat16,
                                                   float* __restrict__ el,
                                                   float* __restrict__ er,
                                                   int* __restrict__ gcnt,
                                                   unsigned* __restrict__ bucket) {
    __shared__ int hist[NBUCK];
    const int t = threadIdx.x;

    if (blockIdx.x < PH1_BLOCKS) {
        // ---- bucket-sort path ----
        const int rg    = blockIdx.x & (NREG - 1);
        const int base  = blockIdx.x * PH1_CHUNK;
        const int cnt_e = min(PH1_CHUNK, E_EDGES - base);   // tail guard
        for (int i = t; i < NBUCK; i += 256) hist[i] = 0;
        __syncthreads();

        unsigned w[16]; int bk[16];
        const i32x4* d4 = (const i32x4*)(dst + base);
        const i32x4* s4 = (const i32x4*)(src + base);
        #pragma unroll
        for (int j4 = 0; j4 < 4; ++j4) {
            int idx = t + j4 * 256;              // int4 index
            int e0  = idx * 4;
            if (e0 + 3 < cnt_e) {
                i32x4 d = d4[idx];
                i32x4 s = s4[idx];
                #pragma unroll
                for (int k = 0; k < 4; ++k) {
                    int jj = j4 * 4 + k;
                    bk[jj] = d[k] >> BSHIFT;
                    w[jj] = ((unsigned)(d[k] & ((1 << BSHIFT) - 1)) << 24) | (unsigned)s[k];
                    atomicAdd(&hist[bk[jj]], 1);
                }
            } else {
                #pragma unroll
                for (int k = 0; k < 4; ++k) {
                    int jj = j4 * 4 + k;
                    bk[jj] = -1;
                    if (e0 + k < cnt_e) {
                        int dj = dst[base + e0 + k];
                        int sj = src[base + e0 + k];
                        bk[jj] = dj >> BSHIFT;
                        w[jj] = ((unsigned)(dj & ((1 << BSHIFT) - 1)) << 24) | (unsigned)sj;
                        atomicAdd(&hist[bk[jj]], 1);
                    }
                }
            }
        }
        __syncthreads();
        // reserve dense runs in the region: hist[b] becomes the write cursor
        for (int i = t; i < NBUCK; i += 256) {
            int c = hist[i];
            hist[i] = (c > 0) ? atomicAdd(&gcnt[rg * NBUCK + i], c) : 0;
        }
        __syncthreads();
        #pragma unroll
        for (int j = 0; j < 16; ++j) {
            if (bk[j] >= 0) {
                int slot = atomicAdd(&hist[bk[j]], 1);
                if (slot < CAPB8)
                    bucket[((size_t)rg * NBUCK + bk[j]) * CAPB8 + slot] = w[j];
            }
        }
        return;
    }

    // ---- GEMM path: 2 row-tiles per wave ----
    const int blk  = blockIdx.x - PH1_BLOCKS;
    const int w    = t >> 6;
    const int lane = t & 63;
    const int lrow = lane & 15;
    const int kq   = lane >> 4;                      // 0..3
    const int gr0  = blk * 128 + w * 32 + lrow;      // tile 0 row
    const int gr1  = gr0 + 16;                       // tile 1 row
    const int r0   = gr0 < N_NODES ? gr0 : N_NODES - 1;
    const int r1   = gr1 < N_NODES ? gr1 : N_NODES - 1;

    f32x4 acc0[8], acc1[8];
    #pragma unroll
    for (int c = 0; c < 8; ++c) {
        acc0[c] = (f32x4){0.f, 0.f, 0.f, 0.f};
        acc1[c] = (f32x4){0.f, 0.f, 0.f, 0.f};
    }

    #pragma unroll
    for (int s = 0; s < 8; ++s) {
        const int k0 = s * 32 + kq * 8;
        float4 u0 = *(const float4*)&x[(size_t)r0 * IN_F + k0];
        float4 u1 = *(const float4*)&x[(size_t)r0 * IN_F + k0 + 4];
        float4 v0 = *(const float4*)&x[(size_t)r1 * IN_F + k0];
        float4 v1 = *(const float4*)&x[(size_t)r1 * IN_F + k0 + 4];
        half8 af0, af1;
        af0[0] = (_Float16)u0.x; af0[1] = (_Float16)u0.y;
        af0[2] = (_Float16)u0.z; af0[3] = (_Float16)u0.w;
        af0[4] = (_Float16)u1.x; af0[5] = (_Float16)u1.y;
        af0[6] = (_Float16)u1.z; af0[7] = (_Float16)u1.w;
        af1[0] = (_Float16)v0.x; af1[1] = (_Float16)v0.y;
        af1[2] = (_Float16)v0.z; af1[3] = (_Float16)v0.w;
        af1[4] = (_Float16)v1.x; af1[5] = (_Float16)v1.y;
        af1[6] = (_Float16)v1.z; af1[7] = (_Float16)v1.w;
        #pragma unroll
        for (int c = 0; c < 8; ++c) {
            half8 bf = *(const half8*)&W16t[(size_t)(c * 16 + lrow) * IN_F + k0];
            acc0[c] = __builtin_amdgcn_mfma_f32_16x16x32_f16(bf, af0, acc0[c], 0, 0, 0);
            acc1[c] = __builtin_amdgcn_mfma_f32_16x16x32_f16(bf, af1, acc1[c], 0, 0, 0);
        }
    }

    // epilogue per tile: fp16 store + fused el/er (col of acc[c][j] = c*16+kq*4+j)
    #pragma unroll
    for (int tile = 0; tile < 2; ++tile) {
        const int gr = tile == 0 ? gr0 : gr1;
        f32x4* acc = tile == 0 ? acc0 : acc1;
        float pl[4] = {0.f, 0.f, 0.f, 0.f}, pr[4] = {0.f, 0.f, 0.f, 0.f};
        #pragma unroll
        for (int c = 0; c < 8; ++c) {
            const int h = c >> 1;
            #pragma unroll
            for (int j = 0; j < 4; ++j) {
                const int col = c * 16 + kq * 4 + j;
                pl[h] += acc[c][j] * attn_l[col];
                pr[h] += acc[c][j] * attn_r[col];
            }
        }
        #pragma unroll
        for (int h = 0; h < 4; ++h) {   // reduce over the 4 kq groups (lane bits 4,5)
            pl[h] += __shfl_xor(pl[h], 16, 64); pl[h] += __shfl_xor(pl[h], 32, 64);
            pr[h] += __shfl_xor(pr[h], 16, 64); pr[h] += __shfl_xor(pr[h], 32, 64);
        }
        if (gr < N_NODES) {
            #pragma unroll
            for (int c = 0; c < 8; ++c) {
                half4v hv;
                hv[0] = (_Float16)acc[c][0]; hv[1] = (_Float16)acc[c][1];
                hv[2] = (_Float16)acc[c][2]; hv[3] = (_Float16)acc[c][3];
                *(half4v*)&feat16[(size_t)gr * HC + c * 16 + kq * 4] = hv;
            }
            if (kq == 0) {
                *(float4*)&el[gr * 4] = make_float4(pl[0], pl[1], pl[2], pl[3]);
                *(float4*)&er[gr * 4] = make_float4(pr[0], pr[1], pr[2], pr[3]);
            }
        }
    }
}

// ---------------- gather: in-LDS CSR + wave-wide weights + 4-node agg -------
__global__ __launch_bounds__(256) void gat_gather(const int* __restrict__ gcnt,
                                                  const unsigned* __restrict__ bucket,
                                                  const float* __restrict__ el,
                                                  const float* __restrict__ er,
                                                  const _Float16* __restrict__ feat16,
                                                  const float* __restrict__ bias,
                                                  float* __restrict__ out) {
    __shared__ int   cnt[64];
    __shared__ int   off[64];
    __shared__ int   lcsr[HALFCAP];
    __shared__ float s_w[4][SWCAP][4];

    const int b   = blockIdx.x >> 1;
    const int sub = blockIdx.x & 1;
    const int t   = threadIdx.x;
    const int n0  = (b << BSHIFT) + sub * 64;

    if (t < 64) cnt[t] = 0;
    __syncthreads();
    #pragma unroll
    for (int rr = 0; rr < NREG; ++rr) {
        const int m = min(gcnt[rr * NBUCK + b], CAPB8);
        const size_t rbase = ((size_t)rr * NBUCK + b) * CAPB8;
        for (int i = t; i < m; i += 256) {
            unsigned wrd = bucket[rbase + i];
            int nb = wrd >> 24;
            if ((nb >> 6) == sub) atomicAdd(&cnt[nb & 63], 1);
        }
    }
    __syncthreads();
    if (t < 64) {   // exclusive scan of 64 counts within wave 0
        int v = cnt[t];
        int inc = v;
        #pragma unroll
        for (int o = 1; o < 64; o <<= 1) {
            int u = __shfl_up(inc, o, 64);
            if (t >= o) inc += u;
        }
        off[t] = inc - v;
        cnt[t] = 0;     // reuse as scatter cursor (restored to count below)
    }
    __syncthreads();
    #pragma unroll
    for (int rr = 0; rr < NREG; ++rr) {
        const int m = min(gcnt[rr * NBUCK + b], CAPB8);
        const size_t rbase = ((size_t)rr * NBUCK + b) * CAPB8;
        for (int i = t; i < m; i += 256) {
            unsigned wrd = bucket[rbase + i];
            int nb = wrd >> 24;
            if ((nb >> 6) == sub) {
                int r = atomicAdd(&cnt[nb & 63], 1);
                int p = off[nb & 63] + r;
                if (p < HALFCAP) lcsr[p] = (int)(wrd & 0xBFFFFFFFu);
            }
        }
    }
    __syncthreads();

    const int wv   = t >> 6;
    const int lane = t & 63;
    const int q    = lane >> 4;      // quarter = node slot
    const int ql   = lane & 15;
    const int h    = ql >> 2;

    // ---- wave-wide weight phase: edges [wbase, wbase+nE) of this wave ----
    const int wbase = off[wv * 16];
    const int wlast = wv * 16 + 15;
    const int nE    = min(off[wlast] + cnt[wlast] - wbase, SWCAP);
    for (int i = lane; i < nE; i += 64) {
        int wrd = lcsr[wbase + i];
        int s   = wrd & 0xFFFFFF;
        int nl  = (wrd >> 24) & 63;
        float4 a  = *(const float4*)&el[(size_t)s * 4];
        float4 bb = *(const float4*)&er[(size_t)(n0 + nl) * 4];
        float v0 = a.x + bb.x, v1 = a.y + bb.y, v2 = a.z + bb.z, v3 = a.w + bb.w;
        v0 = fmaxf(v0, NEG_SLOPE * v0); v1 = fmaxf(v1, NEG_SLOPE * v1);
        v2 = fmaxf(v2, NEG_SLOPE * v2); v3 = fmaxf(v3, NEG_SLOPE * v3);
        float4 w4;
        w4.x = __expf(v0); w4.y = __expf(v1); w4.z = __expf(v2); w4.w = __expf(v3);
        *(float4*)&s_w[wv][i][0] = w4;
    }
    __builtin_amdgcn_sched_barrier(0);   // wave-coherent LDS: DS pipe in-order per wave

    // bias per lane is fixed: channels (ql&3)*8..+7 of head h
    float bv[8];
    #pragma unroll
    for (int k = 0; k < 8; ++k) bv[k] = bias[h * C_FEATS + (ql & 3) * 8 + k];

    // ---- aggregation: 4 rounds x 4 nodes (one per quarter) ----
    for (int r0 = 0; r0 < 16; r0 += 4) {
        const int nl   = wv * 16 + r0 + q;
        const int n    = n0 + nl;
        const int bofs = off[nl];
        const int widx = bofs - wbase;
        int dg = cnt[nl];
        dg = min(dg, SWCAP - widx);
        if (dg < 0 || n >= N_NODES) dg = 0;

        float ac[8] = {0.f, 0.f, 0.f, 0.f, 0.f, 0.f, 0.f, 0.f};
        float sh = 0.f;
        #pragma unroll 4
        for (int j = 0; j < dg; ++j) {
            float wgt = s_w[wv][widx + j][h];
            int s = lcsr[bofs + j] & 0xFFFFFF;
            half8 f = *(const half8*)&feat16[(size_t)s * HC + ql * 8];
            #pragma unroll
            for (int k = 0; k < 8; ++k) ac[k] += wgt * (float)f[k];
            if ((ql & 3) == 0) sh += wgt;
        }
        __builtin_amdgcn_sched_barrier(0);

        // per-head denominator lives at lanes ql%4==0; broadcast within quarter
        float d = __shfl(sh, (lane & 48) | (ql & 12), 64);
        float inv = d > 0.f ? 1.f / d : 0.f;
        float o[8];
        #pragma unroll
        for (int k = 0; k < 8; ++k) o[k] = ac[k] * inv + bv[k];
        // mean over heads: sum across ql bits 2,3 (stays inside the quarter)
        #pragma unroll
        for (int k = 0; k < 8; ++k) {
            o[k] += __shfl_xor(o[k], 4, 64);
            o[k] += __shfl_xor(o[k], 8, 64);
        }
        if (n < N_NODES && ql < 4) {
            float4 r1, r2;
            r1.x = fmaxf(o[0] * 0.25f, 0.f); r1.y = fmaxf(o[1] * 0.25f, 0.f);
            r1.z = fmaxf(o[2] * 0.25f, 0.f); r1.w = fmaxf(o[3] * 0.25f, 0.f);
            r2.x = fmaxf(o[4] * 0.25f, 0.f); r2.y = fmaxf(o[5] * 0.25f, 0.f);
            r2.z = fmaxf(o[6] * 0.25f, 0.f); r2.w = fmaxf(o[7] * 0.25f, 0.f);
            *(float4*)&out[(size_t)n * C_FEATS + ql * 8]     = r1;
            *(float4*)&out[(size_t)n * C_FEATS + ql * 8 + 4] = r2;
        }
    }
}

extern "C" void kernel_launch(void* const* d_in, const int* in_sizes, int n_in,
                              void* d_out, int out_size, void* d_ws, size_t ws_size,
                              hipStream_t stream) {
    const float* x      = (const float*)d_in[0];
    const int*   src    = (const int*)d_in[1];
    const int*   dst    = (const int*)d_in[2];
    const float* W      = (const float*)d_in[3];
    const float* attn_l = (const float*)d_in[4];
    const float* attn_r = (const float*)d_in[5];
    const float* bias   = (const float*)d_in[6];
    float* out = (float*)d_out;

    char* ws = (char*)d_ws;
    const size_t FEAT16_B = (size_t)N_NODES * HC * 2;      // 25.6 MB
    const size_t NH_B     = (size_t)N_NODES * H_HEADS * 4; // 1.6 MB
    size_t off = 0;
    _Float16* feat16 = (_Float16*)(ws + off); off += FEAT16_B;
    float* el        = (float*)(ws + off);    off += NH_B;
    float* er        = (float*)(ws + off);    off += NH_B;
    _Float16* W16t   = (_Float16*)(ws + off); off += (size_t)HC * IN_F * 2;
    int*   gcnt      = (int*)(ws + off);      off += (size_t)NREG * NBUCK * 4;
    off = (off + 255) & ~(size_t)255;
    unsigned* bucket = (unsigned*)(ws + off); off += (size_t)NREG * NBUCK * CAPB8 * 4; // 9.6 MB

    prep_w<<<HC, IN_F, 0, stream>>>(W, W16t, gcnt);
    gemm_bucket<<<PH1_BLOCKS + GEMM_BLOCKS, 256, 0, stream>>>(
        x, W16t, attn_l, attn_r, src, dst, feat16, el, er, gcnt, bucket);
    gat_gather<<<NBUCK * 2, 256, 0, stream>>>(gcnt, bucket, el, er,
                                              feat16, bias, out);
}

// Round 14
// 141.921 us; speedup vs baseline: 1.5449x; 1.0514x over previous
//
#include <hip/hip_runtime.h>
#include <hip/hip_fp16.h>
#include <cstdint>

#define N_NODES 100000
#define H_HEADS 4
#define C_FEATS 32
#define HC 128          // H*C
#define E_EDGES 1600000
#define IN_F 256
#define NEG_SLOPE 0.2f

#define BSHIFT 7                              // bucket = dst >> 7 (128 nodes/bucket)
#define NBUCK 782                             // ceil(100000/128)
#define NREG 8                                // XCD-private region replicas (blockIdx&7)
#define CAPB8 384                             // words per (region,bucket): Poisson(256)+8sd
#define PH1_CHUNK 4096                        // edges per bucket block
#define PH1_BLOCKS ((E_EDGES + PH1_CHUNK - 1) / PH1_CHUNK)   // 391
#define GEMM_BLOCKS ((N_NODES + 127) / 128)   // 782 (128 rows/block, 2 tiles/wave)
#define HALFCAP 1408                          // LDS csr capacity per 64-node sub-block
#define SWCAP 384                             // staged weights per wave (mean 256, +8 sd)

typedef _Float16 half8 __attribute__((ext_vector_type(8)));
typedef _Float16 half4v __attribute__((ext_vector_type(4)));
typedef float f32x4 __attribute__((ext_vector_type(4)));
typedef int i32x4 __attribute__((ext_vector_type(4)));

// ---------------- prep: W16t[c][k] = (fp16) W[k][c]; block 0 zeroes gcnt ----
__global__ __launch_bounds__(256) void prep_w(const float* __restrict__ W,
                                              _Float16* __restrict__ W16t,
                                              int* __restrict__ gcnt) {
    int c = blockIdx.x;      // 0..127
    int k = threadIdx.x;     // 0..255
    W16t[c * IN_F + k] = (_Float16)W[k * HC + c];
    if (c == 0)
        for (int i = k; i < NREG * NBUCK; i += 256) gcnt[i] = 0;
}

// ---------------- fused: bucket-sort blocks + MFMA-GEMM blocks --------------
// Bucket path (R9 form): LDS histogram -> one gcnt atomic per (block,bucket)
// -> contiguous ~5-word runs per line in the XCD-private region (blockIdx&7).
// GEMM path: 2 row-tiles per wave, no min-wave bound (needs >64 VGPR for ILP).
__global__ __launch_bounds__(256) void gemm_bucket(const float* __restrict__ x,
                                                   const _Float16* __restrict__ W16t,
                                                   const float* __restrict__ attn_l,
                                                   const float* __restrict__ attn_r,
                                                   const int* __restrict__ src,
                                                   const int* __restrict__ dst,
                                                   _Float16* __restrict__ feat16,
                                                   float* __restrict__ el,
                                                   float* __restrict__ er,
                                                   int* __restrict__ gcnt,
                                                   unsigned* __restrict__ bucket) {
    __shared__ int hist[NBUCK];
    const int t = threadIdx.x;

    if (blockIdx.x < PH1_BLOCKS) {
        // ---- bucket-sort path ----
        const int rg    = blockIdx.x & (NREG - 1);
        const int base  = blockIdx.x * PH1_CHUNK;
        const int cnt_e = min(PH1_CHUNK, E_EDGES - base);   // tail guard
        for (int i = t; i < NBUCK; i += 256) hist[i] = 0;
        __syncthreads();

        unsigned w[16]; int bk[16];
        const i32x4* d4 = (const i32x4*)(dst + base);
        const i32x4* s4 = (const i32x4*)(src + base);
        #pragma unroll
        for (int j4 = 0; j4 < 4; ++j4) {
            int idx = t + j4 * 256;              // int4 index
            int e0  = idx * 4;
            if (e0 + 3 < cnt_e) {
                i32x4 d = d4[idx];
                i32x4 s = s4[idx];
                #pragma unroll
                for (int k = 0; k < 4; ++k) {
                    int jj = j4 * 4 + k;
                    bk[jj] = d[k] >> BSHIFT;
                    w[jj] = ((unsigned)(d[k] & ((1 << BSHIFT) - 1)) << 24) | (unsigned)s[k];
                    atomicAdd(&hist[bk[jj]], 1);
                }
            } else {
                #pragma unroll
                for (int k = 0; k < 4; ++k) {
                    int jj = j4 * 4 + k;
                    bk[jj] = -1;
                    if (e0 + k < cnt_e) {
                        int dj = dst[base + e0 + k];
                        int sj = src[base + e0 + k];
                        bk[jj] = dj >> BSHIFT;
                        w[jj] = ((unsigned)(dj & ((1 << BSHIFT) - 1)) << 24) | (unsigned)sj;
                        atomicAdd(&hist[bk[jj]], 1);
                    }
                }
            }
        }
        __syncthreads();
        // reserve dense runs in the region: hist[b] becomes the write cursor
        for (int i = t; i < NBUCK; i += 256) {
            int c = hist[i];
            hist[i] = (c > 0) ? atomicAdd(&gcnt[rg * NBUCK + i], c) : 0;
        }
        __syncthreads();
        #pragma unroll
        for (int j = 0; j < 16; ++j) {
            if (bk[j] >= 0) {
                int slot = atomicAdd(&hist[bk[j]], 1);
                if (slot < CAPB8)
                    bucket[((size_t)rg * NBUCK + bk[j]) * CAPB8 + slot] = w[j];
            }
        }
        return;
    }

    // ---- GEMM path: 2 row-tiles per wave ----
    const int blk  = blockIdx.x - PH1_BLOCKS;
    const int w    = t >> 6;
    const int lane = t & 63;
    const int lrow = lane & 15;
    const int kq   = lane >> 4;                      // 0..3
    const int gr0  = blk * 128 + w * 32 + lrow;      // tile 0 row
    const int gr1  = gr0 + 16;                       // tile 1 row
    const int r0   = gr0 < N_NODES ? gr0 : N_NODES - 1;
    const int r1   = gr1 < N_NODES ? gr1 : N_NODES - 1;

    f32x4 acc0[8], acc1[8];
    #pragma unroll
    for (int c = 0; c < 8; ++c) {
        acc0[c] = (f32x4){0.f, 0.f, 0.f, 0.f};
        acc1[c] = (f32x4){0.f, 0.f, 0.f, 0.f};
    }

    #pragma unroll
    for (int s = 0; s < 8; ++s) {
        const int k0 = s * 32 + kq * 8;
        float4 u0 = *(const float4*)&x[(size_t)r0 * IN_F + k0];
        float4 u1 = *(const float4*)&x[(size_t)r0 * IN_F + k0 + 4];
        float4 v0 = *(const float4*)&x[(size_t)r1 * IN_F + k0];
        float4 v1 = *(const float4*)&x[(size_t)r1 * IN_F + k0 + 4];
        half8 af0, af1;
        af0[0] = (_Float16)u0.x; af0[1] = (_Float16)u0.y;
        af0[2] = (_Float16)u0.z; af0[3] = (_Float16)u0.w;
        af0[4] = (_Float16)u1.x; af0[5] = (_Float16)u1.y;
        af0[6] = (_Float16)u1.z; af0[7] = (_Float16)u1.w;
        af1[0] = (_Float16)v0.x; af1[1] = (_Float16)v0.y;
        af1[2] = (_Float16)v0.z; af1[3] = (_Float16)v0.w;
        af1[4] = (_Float16)v1.x; af1[5] = (_Float16)v1.y;
        af1[6] = (_Float16)v1.z; af1[7] = (_Float16)v1.w;
        #pragma unroll
        for (int c = 0; c < 8; ++c) {
            half8 bf = *(const half8*)&W16t[(size_t)(c * 16 + lrow) * IN_F + k0];
            acc0[c] = __builtin_amdgcn_mfma_f32_16x16x32_f16(bf, af0, acc0[c], 0, 0, 0);
            acc1[c] = __builtin_amdgcn_mfma_f32_16x16x32_f16(bf, af1, acc1[c], 0, 0, 0);
        }
    }

    // epilogue per tile: fp16 store + fused el/er (col of acc[c][j] = c*16+kq*4+j)
    #pragma unroll
    for (int tile = 0; tile < 2; ++tile) {
        const int gr = tile == 0 ? gr0 : gr1;
        f32x4* acc = tile == 0 ? acc0 : acc1;
        float pl[4] = {0.f, 0.f, 0.f, 0.f}, pr[4] = {0.f, 0.f, 0.f, 0.f};
        #pragma unroll
        for (int c = 0; c < 8; ++c) {
            const int h = c >> 1;
            #pragma unroll
            for (int j = 0; j < 4; ++j) {
                const int col = c * 16 + kq * 4 + j;
                pl[h] += acc[c][j] * attn_l[col];
                pr[h] += acc[c][j] * attn_r[col];
            }
        }
        #pragma unroll
        for (int h = 0; h < 4; ++h) {   // reduce over the 4 kq groups (lane bits 4,5)
            pl[h] += __shfl_xor(pl[h], 16, 64); pl[h] += __shfl_xor(pl[h], 32, 64);
            pr[h] += __shfl_xor(pr[h], 16, 64); pr[h] += __shfl_xor(pr[h], 32, 64);
        }
        if (gr < N_NODES) {
            #pragma unroll
            for (int c = 0; c < 8; ++c) {
                half4v hv;
                hv[0] = (_Float16)acc[c][0]; hv[1] = (_Float16)acc[c][1];
                hv[2] = (_Float16)acc[c][2]; hv[3] = (_Float16)acc[c][3];
                *(half4v*)&feat16[(size_t)gr * HC + c * 16 + kq * 4] = hv;
            }
            if (kq == 0) {
                *(float4*)&el[gr * 4] = make_float4(pl[0], pl[1], pl[2], pl[3]);
                *(float4*)&er[gr * 4] = make_float4(pr[0], pr[1], pr[2], pr[3]);
            }
        }
    }
}

// ---------------- gather: in-LDS CSR + packed-fp16 weights + 4-node agg -----
// s_w stores each edge's 4 head-weights as 2x half2 (8B/edge): LDS/block
// drops 30.7KB -> 18.4KB => 8 blocks/CU (full 32-wave occupancy). Lanes with
// h in {0,1} ({2,3}) read the SAME dword -> broadcast, then extract half.
__global__ __launch_bounds__(256) void gat_gather(const int* __restrict__ gcnt,
                                                  const unsigned* __restrict__ bucket,
                                                  const float* __restrict__ el,
                                                  const float* __restrict__ er,
                                                  const _Float16* __restrict__ feat16,
                                                  const float* __restrict__ bias,
                                                  float* __restrict__ out) {
    __shared__ int      cnt[64];
    __shared__ int      off[64];
    __shared__ int      lcsr[HALFCAP];
    __shared__ unsigned s_w[4][SWCAP][2];

    const int b   = blockIdx.x >> 1;
    const int sub = blockIdx.x & 1;
    const int t   = threadIdx.x;
    const int n0  = (b << BSHIFT) + sub * 64;

    if (t < 64) cnt[t] = 0;
    __syncthreads();
    #pragma unroll
    for (int rr = 0; rr < NREG; ++rr) {
        const int m = min(gcnt[rr * NBUCK + b], CAPB8);
        const size_t rbase = ((size_t)rr * NBUCK + b) * CAPB8;
        for (int i = t; i < m; i += 256) {
            unsigned wrd = bucket[rbase + i];
            int nb = wrd >> 24;
            if ((nb >> 6) == sub) atomicAdd(&cnt[nb & 63], 1);
        }
    }
    __syncthreads();
    if (t < 64) {   // exclusive scan of 64 counts within wave 0
        int v = cnt[t];
        int inc = v;
        #pragma unroll
        for (int o = 1; o < 64; o <<= 1) {
            int u = __shfl_up(inc, o, 64);
            if (t >= o) inc += u;
        }
        off[t] = inc - v;
        cnt[t] = 0;     // reuse as scatter cursor (restored to count below)
    }
    __syncthreads();
    #pragma unroll
    for (int rr = 0; rr < NREG; ++rr) {
        const int m = min(gcnt[rr * NBUCK + b], CAPB8);
        const size_t rbase = ((size_t)rr * NBUCK + b) * CAPB8;
        for (int i = t; i < m; i += 256) {
            unsigned wrd = bucket[rbase + i];
            int nb = wrd >> 24;
            if ((nb >> 6) == sub) {
                int r = atomicAdd(&cnt[nb & 63], 1);
                int p = off[nb & 63] + r;
                if (p < HALFCAP) lcsr[p] = (int)(wrd & 0xBFFFFFFFu);
            }
        }
    }
    __syncthreads();

    const int wv   = t >> 6;
    const int lane = t & 63;
    const int q    = lane >> 4;      // quarter = node slot
    const int ql   = lane & 15;
    const int h    = ql >> 2;

    // ---- wave-wide weight phase: edges [wbase, wbase+nE) of this wave ----
    const int wbase = off[wv * 16];
    const int wlast = wv * 16 + 15;
    const int nE    = min(off[wlast] + cnt[wlast] - wbase, SWCAP);
    for (int i = lane; i < nE; i += 64) {
        int wrd = lcsr[wbase + i];
        int s   = wrd & 0xFFFFFF;
        int nl  = (wrd >> 24) & 63;
        float4 a  = *(const float4*)&el[(size_t)s * 4];
        float4 bb = *(const float4*)&er[(size_t)(n0 + nl) * 4];
        float v0 = a.x + bb.x, v1 = a.y + bb.y, v2 = a.z + bb.z, v3 = a.w + bb.w;
        v0 = fmaxf(v0, NEG_SLOPE * v0); v1 = fmaxf(v1, NEG_SLOPE * v1);
        v2 = fmaxf(v2, NEG_SLOPE * v2); v3 = fmaxf(v3, NEG_SLOPE * v3);
        __half2 p01 = __floats2half2_rn(__expf(v0), __expf(v1));
        __half2 p23 = __floats2half2_rn(__expf(v2), __expf(v3));
        s_w[wv][i][0] = *(unsigned*)&p01;
        s_w[wv][i][1] = *(unsigned*)&p23;
    }
    __builtin_amdgcn_sched_barrier(0);   // wave-coherent LDS: DS pipe in-order per wave

    // bias per lane is fixed: channels (ql&3)*8..+7 of head h
    float bv[8];
    #pragma unroll
    for (int k = 0; k < 8; ++k) bv[k] = bias[h * C_FEATS + (ql & 3) * 8 + k];

    // ---- aggregation: 4 rounds x 4 nodes (one per quarter) ----
    for (int r0 = 0; r0 < 16; r0 += 4) {
        const int nl   = wv * 16 + r0 + q;
        const int n    = n0 + nl;
        const int bofs = off[nl];
        const int widx = bofs - wbase;
        int dg = cnt[nl];
        dg = min(dg, SWCAP - widx);
        if (dg < 0 || n >= N_NODES) dg = 0;

        float ac[8] = {0.f, 0.f, 0.f, 0.f, 0.f, 0.f, 0.f, 0.f};
        float sh = 0.f;
        #pragma unroll 4
        for (int j = 0; j < dg; ++j) {
            unsigned pw = s_w[wv][widx + j][h >> 1];
            __half2 hp = *(__half2*)&pw;
            float wgt = (h & 1) ? __high2float(hp) : __low2float(hp);
            int s = lcsr[bofs + j] & 0xFFFFFF;
            half8 f = *(const half8*)&feat16[(size_t)s * HC + ql * 8];
            #pragma unroll
            for (int k = 0; k < 8; ++k) ac[k] += wgt * (float)f[k];
            if ((ql & 3) == 0) sh += wgt;
        }
        __builtin_amdgcn_sched_barrier(0);

        // per-head denominator lives at lanes ql%4==0; broadcast within quarter
        float d = __shfl(sh, (lane & 48) | (ql & 12), 64);
        float inv = d > 0.f ? 1.f / d : 0.f;
        float o[8];
        #pragma unroll
        for (int k = 0; k < 8; ++k) o[k] = ac[k] * inv + bv[k];
        // mean over heads: sum across ql bits 2,3 (stays inside the quarter)
        #pragma unroll
        for (int k = 0; k < 8; ++k) {
            o[k] += __shfl_xor(o[k], 4, 64);
            o[k] += __shfl_xor(o[k], 8, 64);
        }
        if (n < N_NODES && ql < 4) {
            float4 r1, r2;
            r1.x = fmaxf(o[0] * 0.25f, 0.f); r1.y = fmaxf(o[1] * 0.25f, 0.f);
            r1.z = fmaxf(o[2] * 0.25f, 0.f); r1.w = fmaxf(o[3] * 0.25f, 0.f);
            r2.x = fmaxf(o[4] * 0.25f, 0.f); r2.y = fmaxf(o[5] * 0.25f, 0.f);
            r2.z = fmaxf(o[6] * 0.25f, 0.f); r2.w = fmaxf(o[7] * 0.25f, 0.f);
            *(float4*)&out[(size_t)n * C_FEATS + ql * 8]     = r1;
            *(float4*)&out[(size_t)n * C_FEATS + ql * 8 + 4] = r2;
        }
    }
}

extern "C" void kernel_launch(void* const* d_in, const int* in_sizes, int n_in,
                              void* d_out, int out_size, void* d_ws, size_t ws_size,
                              hipStream_t stream) {
    const float* x      = (const float*)d_in[0];
    const int*   src    = (const int*)d_in[1];
    const int*   dst    = (const int*)d_in[2];
    const float* W      = (const float*)d_in[3];
    const float* attn_l = (const float*)d_in[4];
    const float* attn_r = (const float*)d_in[5];
    const float* bias   = (const float*)d_in[6];
    float* out = (float*)d_out;

    char* ws = (char*)d_ws;
    const size_t FEAT16_B = (size_t)N_NODES * HC * 2;      // 25.6 MB
    const size_t NH_B     = (size_t)N_NODES * H_HEADS * 4; // 1.6 MB
    size_t off = 0;
    _Float16* feat16 = (_Float16*)(ws + off); off += FEAT16_B;
    float* el        = (float*)(ws + off);    off += NH_B;
    float* er        = (float*)(ws + off);    off += NH_B;
    _Float16* W16t   = (_Float16*)(ws + off); off += (size_t)HC * IN_F * 2;
    int*   gcnt      = (int*)(ws + off);      off += (size_t)NREG * NBUCK * 4;
    off = (off + 255) & ~(size_t)255;
    unsigned* bucket = (unsigned*)(ws + off); off += (size_t)NREG * NBUCK * CAPB8 * 4; // 9.6 MB

    prep_w<<<HC, IN_F, 0, stream>>>(W, W16t, gcnt);
    gemm_bucket<<<PH1_BLOCKS + GEMM_BLOCKS, 256, 0, stream>>>(
        x, W16t, attn_l, attn_r, src, dst, feat16, el, er, gcnt, bucket);
    gat_gather<<<NBUCK * 2, 256, 0, stream>>>(gcnt, bucket, el, er,
                                              feat16, bias, out);
}